// Round 1
// baseline (13.511 us; speedup 1.0000x reference)
//
#include <hip/hip_runtime.h>

#define NCLS   80
#define NBINS  16
#define T_TGT  64
#define B_IMG  32
#define N_TGT  (B_IMG * T_TGT)   // 2048
#define N_DFL  (3 * B_IMG)       // 96

// One 64-lane wave per target (focal cls loss) + one wave per (layer,image)
// pair (DFL box loss). Per-wave partial losses written to ws; reduced by a
// second tiny kernel (deterministic: fixed order, no float atomics).
__global__ __launch_bounds__(256) void detloss_main(
    const float* __restrict__ feat0,
    const float* __restrict__ feat1,
    const float* __restrict__ feat2,
    const float* __restrict__ tgt_box,
    const int*   __restrict__ tgt_cls,
    const int*   __restrict__ tgt_layer,
    float* __restrict__ ws)
{
    const int wave = (blockIdx.x * blockDim.x + threadIdx.x) >> 6;
    const int lane = threadIdx.x & 63;

    if (wave < N_TGT) {
        // ---------------- focal classification loss: one wave per target ----
        const int b = wave >> 6;       // wave / T_TGT
        const int t = wave & 63;
        const int bt = b * T_TGT + t;
        const int li = tgt_layer[bt];  // target's own layer (mask == exact match)

        const float* feat; int H, W;
        if (li == 0)      { feat = feat0; H = 80; W = 80; }
        else if (li == 1) { feat = feat1; H = 40; W = 40; }
        else              { feat = feat2; H = 20; W = 20; }

        const float cx = tgt_box[bt * 4 + 0];
        const float cy = tgt_box[bt * 4 + 1];
        int fx = (int)(cx * (float)W); fx = min(max(fx, 0), W - 1);
        int fy = (int)(cy * (float)H); fy = min(max(fy, 0), H - 1);

        const int HW = H * W;
        const float* pix = feat + (size_t)b * 144 * HW + fy * W + fx;

        // class logits live in channels 64..143; channel stride = HW floats
        const float v0 = pix[(size_t)(64 + lane) * HW];
        const float v1 = (lane < 16) ? pix[(size_t)(128 + lane) * HW] : -INFINITY;

        // wave-wide max
        float m = fmaxf(v0, v1);
        #pragma unroll
        for (int off = 32; off >= 1; off >>= 1)
            m = fmaxf(m, __shfl_xor(m, off));

        // wave-wide sum of exp
        float s = expf(v0 - m) + ((lane < 16) ? expf(v1 - m) : 0.0f);
        #pragma unroll
        for (int off = 32; off >= 1; off >>= 1)
            s += __shfl_xor(s, off);

        // broadcast logit of the target class (tc is wave-uniform)
        const int tc = tgt_cls[bt];
        float sel;
        if (tc < 64) sel = __shfl(v0, tc);
        else         sel = __shfl(v1, tc - 64);

        const float ce = m + logf(s) - sel;     // -log_softmax[tc]
        const float pt = expf(-ce);
        const float om = 1.0f - pt;
        const float focal = om * om * ce;

        if (lane == 0) ws[wave] = focal;
    } else if (wave < N_TGT + N_DFL) {
        // ---------------- DFL box loss: one wave per (layer, image) ---------
        const int w2 = wave - N_TGT;
        const int li = w2 >> 5;        // 0..2
        const int b  = w2 & 31;        // 0..31

        // find LAST target t in image b with tgt_layer == li
        const int my_layer = tgt_layer[b * T_TGT + lane];
        const unsigned long long msk = __ballot(my_layer == li);
        if (msk == 0ull) {
            if (lane == 0) ws[N_TGT + w2] = 0.0f;
            return;
        }
        const int last = 63 - __clzll(msk);
        const int bt = b * T_TGT + last;

        const float* feat; int H, W;
        if (li == 0)      { feat = feat0; H = 80; W = 80; }
        else if (li == 1) { feat = feat1; H = 40; W = 40; }
        else              { feat = feat2; H = 20; W = 20; }

        const float cx = tgt_box[bt * 4 + 0];
        const float cy = tgt_box[bt * 4 + 1];
        const float bw = tgt_box[bt * 4 + 2];
        const float bh = tgt_box[bt * 4 + 3];
        int fx = (int)(cx * (float)W); fx = min(max(fx, 0), W - 1);
        int fy = (int)(cy * (float)H); fy = min(max(fy, 0), H - 1);

        const int HW = H * W;
        const float* pix = feat + (size_t)b * 144 * HW + fy * W + fx;

        // dist logits: channels 0..63; lane l -> anchor a = l>>4, bin k = l&15
        const float v = pix[(size_t)lane * HW];
        const int a = lane >> 4;
        const int k = lane & 15;

        // per-16-lane-group (per-anchor) log-softmax via xor shuffles (stay
        // inside the 16-lane group for offsets 1,2,4,8)
        float gm = v;
        #pragma unroll
        for (int off = 8; off >= 1; off >>= 1)
            gm = fmaxf(gm, __shfl_xor(gm, off));
        float gs = expf(v - gm);
        #pragma unroll
        for (int off = 8; off >= 1; off >>= 1)
            gs += __shfl_xor(gs, off);
        const float lps = v - gm - logf(gs);    // log_softmax value at bin k

        // target distance for this anchor: gt = {lw*W, lh*H, lw*W, lh*H}
        const float lw = fmaxf(bw, 0.0f) * 0.5f;
        const float lh = fmaxf(bh, 0.0f) * 0.5f;
        float ta = (a & 1) ? (lh * (float)H) : (lw * (float)W);
        ta = fminf(fmaxf(ta, 0.0f), (float)(NBINS - 1) - 1e-6f);
        const float lo = floorf(ta);
        const float wl = lo + 1.0f - ta;
        const float wr = ta - lo;
        const int lo_i = (int)lo;
        const int hi_i = min(lo_i + 1, NBINS - 1);

        float contrib = 0.0f;
        if (k == lo_i) contrib += -lps * wl;
        if (k == hi_i) contrib += -lps * wr;

        // sum across wave (covers all 4 anchors)
        #pragma unroll
        for (int off = 32; off >= 1; off >>= 1)
            contrib += __shfl_xor(contrib, off);

        if (lane == 0) ws[N_TGT + w2] = contrib;
    }
}

__global__ __launch_bounds__(256) void detloss_reduce(
    const float* __restrict__ ws, float* __restrict__ out)
{
    __shared__ float scls[256];
    __shared__ float sbox[256];
    const int tid = threadIdx.x;

    float c = 0.0f, bx = 0.0f;
    for (int i = tid; i < N_TGT; i += 256) c += ws[i];
    for (int i = tid; i < N_DFL; i += 256) bx += ws[N_TGT + i];
    scls[tid] = c; sbox[tid] = bx;
    __syncthreads();
    #pragma unroll
    for (int s = 128; s > 0; s >>= 1) {
        if (tid < s) { scls[tid] += scls[tid + s]; sbox[tid] += sbox[tid + s]; }
        __syncthreads();
    }
    if (tid == 0) {
        const float cls_tot = scls[0];
        const float box_tot = sbox[0];
        out[0] = cls_tot + box_tot;  // total (CLS_W = BOX_W = 1)
        out[1] = cls_tot;
        out[2] = box_tot;
    }
}

extern "C" void kernel_launch(void* const* d_in, const int* in_sizes, int n_in,
                              void* d_out, int out_size, void* d_ws, size_t ws_size,
                              hipStream_t stream) {
    const float* feat0    = (const float*)d_in[0];
    const float* feat1    = (const float*)d_in[1];
    const float* feat2    = (const float*)d_in[2];
    const float* tgt_box  = (const float*)d_in[3];
    const int*   tgt_cls  = (const int*)d_in[4];
    const int*   tgt_layer= (const int*)d_in[5];
    float* out = (float*)d_out;
    float* ws  = (float*)d_ws;

    // (N_TGT + N_DFL) waves = 2144 waves = 536 blocks of 256 threads (4 waves)
    const int n_waves = N_TGT + N_DFL;
    const int blocks = (n_waves * 64 + 255) / 256;

    detloss_main<<<blocks, 256, 0, stream>>>(feat0, feat1, feat2,
                                             tgt_box, tgt_cls, tgt_layer, ws);
    detloss_reduce<<<1, 256, 0, stream>>>(ws, out);
}